// Round 11
// baseline (994.534 us; speedup 1.0000x reference)
//
#include <hip/hip_runtime.h>
#include <math.h>

#define NA 10000      // atoms
#define NE 160000     // edges
#define NG 100        // graphs
#define DF 128
#define NL 5
#define NAP 10112     // NA padded to 128-row tiles (79*128)
#define NSB 40        // scan blocks = ceil(NA/256)

typedef __attribute__((ext_vector_type(8))) short bfx8;
typedef __attribute__((ext_vector_type(4))) float f32x4;

__device__ __forceinline__ float silu_f(float x) {
    return x / (1.0f + __expf(-x));
}

__device__ __forceinline__ unsigned short f2bf(float x) {
    unsigned u = __builtin_bit_cast(unsigned, x);
    u = (u + 0x7FFFu + ((u >> 16) & 1u)) >> 16;
    return (unsigned short)u;
}
__device__ __forceinline__ float bf2f(unsigned short h) {
    unsigned u = ((unsigned)h) << 16;
    return __builtin_bit_cast(float, u);
}
__device__ __forceinline__ unsigned packbf(float lo, float hi) {
    return (unsigned)f2bf(lo) | ((unsigned)f2bf(hi) << 16);
}

__device__ __forceinline__ void sph9(float dx, float dy, float dz, float* s) {
    float r = sqrtf(dx * dx + dy * dy + dz * dz);
    float inv = 1.0f / fmaxf(r, 1e-12f);
    float x = dx * inv, y = dy * inv, z = dz * inv;
    const float S3 = 1.7320508075688772f;
    s[0] = 1.0f;
    s[1] = x; s[2] = y; s[3] = z;
    s[4] = S3 * x * z;
    s[5] = S3 * x * y;
    s[6] = y * y - 0.5f * (x * x + z * z);
    s[7] = S3 * y * z;
    s[8] = 0.5f * S3 * (z * z - x * x);
}

// ---------------- weight prep: transpose + bf16 ------------------------------
#define OFF_SIRC  0        // si1 pair [2][128][128]
#define OFF_SICTR 32768    // siC1 [128][128]
#define LBASE     49152
#define LOFF_MRC  0        // m1 pair [2][128][128]
#define LOFF_M2   32768
#define LOFF_P1   49152
#define LOFF_S1   65536
#define LOFF_N1   81920    // [128][256]
#define LOFF_N2   114688
#define LSIZE     131072
#define WT_TOTAL  704512   // 49152 + 5*131072

__global__ void k_prep_w(const float* __restrict__ Wsi1, const float* __restrict__ WsiC1,
                         const float* __restrict__ Wm1, const float* __restrict__ Wm2,
                         const float* __restrict__ Wp1, const float* __restrict__ Ws1,
                         const float* __restrict__ Wn1, const float* __restrict__ Wn2,
                         unsigned short* __restrict__ WT) {
    int flat = blockIdx.x * 256 + threadIdx.x;
    if (flat >= WT_TOTAL) return;
    float v = 0.0f;
    if (flat < OFF_SICTR) {                      // si1 pair: rows 1..128 / 129..256
        int half = flat >> 14;
        int o = flat & 16383;
        int n = o >> 7, k = o & 127;
        v = Wsi1[(k + 1 + half * 128) * 128 + n];
    } else if (flat < LBASE) {                   // siC1
        int o = flat - OFF_SICTR;
        int n = o >> 7, k = o & 127;
        v = WsiC1[k * 128 + n];
    } else {
        int t = flat - LBASE;
        int lyr = t / LSIZE;
        int o = t % LSIZE;
        if (o < LOFF_M2) {                       // m1 pair
            int half = o >> 14;
            int o2 = o & 16383;
            int n = o2 >> 7, k = o2 & 127;
            v = Wm1[(size_t)lyr * 33280 + (k + half * 128) * 128 + n];
        } else if (o < LOFF_P1) {
            int o2 = o - LOFF_M2; int n = o2 >> 7, k = o2 & 127;
            v = Wm2[(size_t)lyr * 16384 + k * 128 + n];
        } else if (o < LOFF_S1) {
            int o2 = o - LOFF_P1; int n = o2 >> 7, k = o2 & 127;
            v = Wp1[(size_t)lyr * 16384 + k * 128 + n];
        } else if (o < LOFF_N1) {
            int o2 = o - LOFF_S1; int n = o2 >> 7, k = o2 & 127;
            v = Ws1[(size_t)lyr * 16384 + k * 128 + n];
        } else if (o < LOFF_N2) {
            int o2 = o - LOFF_N1; int n = o2 >> 8, k = o2 & 255;
            v = Wn1[(size_t)lyr * 32768 + k * 128 + n];
        } else {
            int o2 = o - LOFF_N2; int n = o2 >> 7, k = o2 & 127;
            v = Wn2[(size_t)lyr * 16384 + k * 128 + n];
        }
    }
    WT[flat] = f2bf(v);
}

// ---------------- F-pair node GEMM: F12[y] = featb @ WT2[y]  (no bias/act) ---
__global__ __launch_bounds__(256) void k_fgemm(
    const unsigned short* __restrict__ Ab,    // featb [NAP][128]
    const unsigned short* __restrict__ WT2,   // [2][128][128]
    unsigned short* __restrict__ F12)         // [2][NAP][128]
{
    __shared__ unsigned short As[128 * 40];
    __shared__ unsigned short Bs[128 * 40];
    const unsigned short* WTp = WT2 + (size_t)blockIdx.y * 16384;
    unsigned short* Cb = F12 + (size_t)blockIdx.y * NAP * 128;

    const int tid = threadIdx.x;
    const int m0 = blockIdx.x * 128;
    const int mlo = tid >> 2;
    const int part = tid & 3;
    const int w = tid >> 6, l = tid & 63;
    const int quad = l >> 4, lm = l & 15;
    const int wm = (w >> 1) * 64, wn = (w & 1) * 64;

    f32x4 acc[4][4] = {};
#pragma unroll 1
    for (int c = 0; c < 4; c++) {
        const int k0 = c * 32;
#pragma unroll
        for (int i = 0; i < 2; i++) {
            const int m = mlo + i * 64;
            *(uint4*)&As[m * 40 + part * 8] =
                *(const uint4*)(Ab + (size_t)(m0 + m) * 128 + k0 + part * 8);
            *(uint4*)&Bs[m * 40 + part * 8] =
                *(const uint4*)(WTp + (size_t)m * 128 + k0 + part * 8);
        }
        __syncthreads();
        bfx8 a[4], b[4];
#pragma unroll
        for (int i = 0; i < 4; i++) a[i] = *(const bfx8*)&As[(wm + i * 16 + lm) * 40 + quad * 8];
#pragma unroll
        for (int j = 0; j < 4; j++) b[j] = *(const bfx8*)&Bs[(wn + j * 16 + lm) * 40 + quad * 8];
#pragma unroll
        for (int i = 0; i < 4; i++)
#pragma unroll
            for (int j = 0; j < 4; j++)
                acc[i][j] = __builtin_amdgcn_mfma_f32_16x16x32_bf16(a[i], b[j], acc[i][j], 0, 0, 0);
        __syncthreads();
    }
#pragma unroll
    for (int i = 0; i < 4; i++) {
        const int rbase = wm + i * 16 + quad * 4;
#pragma unroll
        for (int r = 0; r < 4; r++) {
            const int e = m0 + rbase + r;
#pragma unroll
            for (int j = 0; j < 4; j++)
                Cb[(size_t)e * 128 + wn + j * 16 + lm] = f2bf(acc[i][j][r]);
        }
    }
}

// ---------------- LDS-staged MFMA GEMM (R8 structure) ------------------------
template <int KP, bool ACT, int NOUT, bool F32OUT>
__global__ __launch_bounds__(256) void gemm_mfma(
    const unsigned short* __restrict__ Ab,
    const unsigned short* __restrict__ WT,
    const float* __restrict__ bias, int M,
    unsigned short* __restrict__ Cb, float* __restrict__ Cf,
    const float* __restrict__ W2, const float* __restrict__ b2,
    float* __restrict__ outS)
{
    constexpr int NO = (NOUT > 0) ? NOUT : 1;
    __shared__ unsigned short As[128 * 40];
    __shared__ unsigned short Bs[128 * 40];
    __shared__ float W2s[NOUT > 0 ? 128 * NO : 1];
    __shared__ float red[NOUT > 0 ? 128 * 8 * NO : 1];

    const int tid = threadIdx.x;
    const int m0 = blockIdx.x * 128;
    const int mlo = tid >> 2;
    const int part = tid & 3;

    if (NOUT > 0) {
        for (int t = tid; t < 128 * NO; t += 256) W2s[t] = W2[t];
    }

    const int w = tid >> 6, l = tid & 63;
    const int quad = l >> 4, lm = l & 15;
    const int wm = (w >> 1) * 64, wn = (w & 1) * 64;

    float bv[4];
#pragma unroll
    for (int j = 0; j < 4; j++) bv[j] = bias[wn + j * 16 + lm];

    f32x4 acc[4][4] = {};
    constexpr int NCH = KP / 32;
#pragma unroll 1
    for (int c = 0; c < NCH; c++) {
        const int k0 = c * 32;
#pragma unroll
        for (int i = 0; i < 2; i++) {
            const int m = mlo + i * 64;
            *(uint4*)&As[m * 40 + part * 8] =
                *(const uint4*)(Ab + (size_t)(m0 + m) * KP + k0 + part * 8);
            *(uint4*)&Bs[m * 40 + part * 8] =
                *(const uint4*)(WT + (size_t)m * KP + k0 + part * 8);
        }
        __syncthreads();
        bfx8 a[4], b[4];
#pragma unroll
        for (int i = 0; i < 4; i++) a[i] = *(const bfx8*)&As[(wm + i * 16 + lm) * 40 + quad * 8];
#pragma unroll
        for (int j = 0; j < 4; j++) b[j] = *(const bfx8*)&Bs[(wn + j * 16 + lm) * 40 + quad * 8];
#pragma unroll
        for (int i = 0; i < 4; i++)
#pragma unroll
            for (int j = 0; j < 4; j++)
                acc[i][j] = __builtin_amdgcn_mfma_f32_16x16x32_bf16(a[i], b[j], acc[i][j], 0, 0, 0);
        __syncthreads();
    }

    if (NOUT > 0) {
        const int slot = (w & 1) * 4 + (lm >> 2);
#pragma unroll
        for (int i = 0; i < 4; i++) {
#pragma unroll
            for (int r = 0; r < 4; r++) {
                const int rowL = wm + i * 16 + quad * 4 + r;
                float ps[NO];
#pragma unroll
                for (int o = 0; o < NO; o++) ps[o] = 0.0f;
#pragma unroll
                for (int j = 0; j < 4; j++) {
                    float v = silu_f(acc[i][j][r] + bv[j]);
                    const int colg = wn + j * 16 + lm;
#pragma unroll
                    for (int o = 0; o < NO; o++) ps[o] += v * W2s[colg * NO + o];
                }
#pragma unroll
                for (int off = 1; off <= 2; off <<= 1)
#pragma unroll
                    for (int o = 0; o < NO; o++) ps[o] += __shfl_xor(ps[o], off, 64);
                if ((lm & 3) == 0)
#pragma unroll
                    for (int o = 0; o < NO; o++)
                        red[(rowL * 8 + slot) * NO + o] = ps[o];
            }
        }
        __syncthreads();
        for (int t = tid; t < 128 * NO; t += 256) {
            int rowL = t / NO, o = t - rowL * NO;
            float s = 0.0f;
#pragma unroll
            for (int k = 0; k < 8; k++) s += red[(rowL * 8 + k) * NO + o];
            int e = m0 + rowL;
            if (e < M) outS[(size_t)e * NO + o] = s + b2[o];
        }
    } else {
#pragma unroll
        for (int i = 0; i < 4; i++) {
            const int rbase = wm + i * 16 + quad * 4;
#pragma unroll
            for (int r = 0; r < 4; r++) {
                const int e = m0 + rbase + r;
                if (e >= M) continue;
#pragma unroll
                for (int j = 0; j < 4; j++) {
                    float v = acc[i][j][r] + bv[j];
                    if (ACT) v = silu_f(v);
                    const int colg = wn + j * 16 + lm;
                    Cb[(size_t)e * 128 + colg] = f2bf(v);
                    if (F32OUT) Cf[(size_t)e * 128 + colg] = v;
                }
            }
        }
    }
}

// ---------------- fused edge-h + m2 GEMM -------------------------------------
// A-staging computes h = silu(F1[row] + F2[col] + tail@Wt + b1) on the fly
// (bf16-packed, numerically identical to the k_edge_h -> bufHb -> m2 path),
// then m = silu(h @ w2 + b2) -> bufMb. Kills the 82 MB/layer bufHb round-trip.
__global__ __launch_bounds__(256) void k_m2f(
    const int* __restrict__ rowI, const int* __restrict__ colI,
    const unsigned short* __restrict__ F12,    // [2][NAP][128]
    const float* __restrict__ pos, const float* __restrict__ sh,
    const float* __restrict__ wtail,           // [4][128] fp32 (Wm1 rows 256..259)
    const float* __restrict__ b1,
    const unsigned short* __restrict__ w2,     // [128][128] bf16 [n][k]
    const float* __restrict__ b2,
    unsigned short* __restrict__ bufMb)
{
    __shared__ unsigned short As[128 * 40];
    __shared__ unsigned short Bs[128 * 40];
    __shared__ float Wtj[128][4];   // j-major tail weights (float4 per j)
    __shared__ float B1[128];
    __shared__ float tail4[128][4]; // per-edge {d2, ip0, ip1, ip2}

    const int tid = threadIdx.x;
    const int m0 = blockIdx.x * 128;
    if (tid < 128) B1[tid] = b1[tid];
    for (int t = tid; t < 512; t += 256) Wtj[t & 127][t >> 7] = wtail[t];

    const int mlo = tid >> 2;
    const int part = tid & 3;
    const int er0 = rowI[m0 + mlo],      ec0 = colI[m0 + mlo];
    const int er1 = rowI[m0 + mlo + 64], ec1 = colI[m0 + mlo + 64];

    if (part == 0) {
#pragma unroll
        for (int i = 0; i < 2; i++) {
            int r = i ? er1 : er0, c = i ? ec1 : ec0;
            int erow = mlo + i * 64;
            float dx = pos[r * 3 + 0] - pos[c * 3 + 0];
            float dy = pos[r * 3 + 1] - pos[c * 3 + 1];
            float dz = pos[r * 3 + 2] - pos[c * 3 + 2];
            const float* sr = sh + (size_t)r * 9;
            const float* sc = sh + (size_t)c * 9;
            tail4[erow][0] = dx * dx + dy * dy + dz * dz;
            tail4[erow][1] = sr[0] * sc[0];
            tail4[erow][2] = sr[1] * sc[1] + sr[2] * sc[2] + sr[3] * sc[3];
            tail4[erow][3] = sr[4] * sc[4] + sr[5] * sc[5] + sr[6] * sc[6]
                           + sr[7] * sc[7] + sr[8] * sc[8];
        }
    }

    const int w = tid >> 6, l = tid & 63;
    const int quad = l >> 4, lm = l & 15;
    const int wm = (w >> 1) * 64, wn = (w & 1) * 64;

    float bv[4];
#pragma unroll
    for (int j = 0; j < 4; j++) bv[j] = b2[wn + j * 16 + lm];

    __syncthreads();   // tail4 / Wtj / B1 ready

    float t4a[4], t4b[4];
    *(float4*)t4a = *(const float4*)tail4[mlo];
    *(float4*)t4b = *(const float4*)tail4[mlo + 64];

    f32x4 acc[4][4] = {};
#pragma unroll 1
    for (int c = 0; c < 4; c++) {
        const int k0 = c * 32;
        const int j0b = k0 + part * 8;
#pragma unroll
        for (int i = 0; i < 2; i++) {
            const int erow = mlo + i * 64;
            const int er = i ? er1 : er0;
            const int ec = i ? ec1 : ec0;
            const float* tl = i ? t4b : t4a;
            uint4 a = *(const uint4*)(F12 + (size_t)er * 128 + j0b);
            uint4 b = *(const uint4*)(F12 + (size_t)NAP * 128 + (size_t)ec * 128 + j0b);
            unsigned av[4] = {a.x, a.y, a.z, a.w};
            unsigned bvv[4] = {b.x, b.y, b.z, b.w};
            unsigned ov[4];
#pragma unroll
            for (int q = 0; q < 4; q++) {
                int j0 = j0b + q * 2;
                float4 wj0 = *(const float4*)Wtj[j0];
                float4 wj1 = *(const float4*)Wtj[j0 + 1];
                float h0 = bf2f((unsigned short)(av[q] & 0xFFFFu)) + bf2f((unsigned short)(bvv[q] & 0xFFFFu))
                         + tl[0] * wj0.x + tl[1] * wj0.y + tl[2] * wj0.z + tl[3] * wj0.w + B1[j0];
                float h1 = bf2f((unsigned short)(av[q] >> 16)) + bf2f((unsigned short)(bvv[q] >> 16))
                         + tl[0] * wj1.x + tl[1] * wj1.y + tl[2] * wj1.z + tl[3] * wj1.w + B1[j0 + 1];
                ov[q] = packbf(silu_f(h0), silu_f(h1));
            }
            *(uint4*)&As[erow * 40 + part * 8] = make_uint4(ov[0], ov[1], ov[2], ov[3]);
            *(uint4*)&Bs[erow * 40 + part * 8] =
                *(const uint4*)(w2 + (size_t)erow * 128 + k0 + part * 8);
        }
        __syncthreads();
        bfx8 a[4], b[4];
#pragma unroll
        for (int i = 0; i < 4; i++) a[i] = *(const bfx8*)&As[(wm + i * 16 + lm) * 40 + quad * 8];
#pragma unroll
        for (int j = 0; j < 4; j++) b[j] = *(const bfx8*)&Bs[(wn + j * 16 + lm) * 40 + quad * 8];
#pragma unroll
        for (int i = 0; i < 4; i++)
#pragma unroll
            for (int j = 0; j < 4; j++)
                acc[i][j] = __builtin_amdgcn_mfma_f32_16x16x32_bf16(a[i], b[j], acc[i][j], 0, 0, 0);
        __syncthreads();
    }

#pragma unroll
    for (int i = 0; i < 4; i++) {
        const int rbase = wm + i * 16 + quad * 4;
#pragma unroll
        for (int r = 0; r < 4; r++) {
            const int e = m0 + rbase + r;
#pragma unroll
            for (int j = 0; j < 4; j++) {
                float v = silu_f(acc[i][j][r] + bv[j]);
                bufMb[(size_t)e * 128 + wn + j * 16 + lm] = f2bf(v);
            }
        }
    }
}

// ---------------- streaming edge kernel (init si) ----------------------------
__global__ __launch_bounds__(256) void k_edge_si(
    const int* __restrict__ rowI, const int* __restrict__ colI,
    const unsigned short* __restrict__ F12,    // [2][NAP][128]
    const float* __restrict__ pos,
    const float* __restrict__ Wsi1,            // row 0 = dist weights [128]
    const float* __restrict__ b1,
    const float* __restrict__ W2,              // [128][3]
    const float* __restrict__ b2,
    float* __restrict__ outS)                  // [NE][3]
{
    __shared__ float Wd[128];
    __shared__ float B1[128];
    __shared__ float W2s[128 * 3];
    int tid = threadIdx.x;
    if (tid < 128) { Wd[tid] = Wsi1[tid]; B1[tid] = b1[tid]; }
    for (int t = tid; t < 384; t += 256) W2s[t] = W2[t];
    __syncthreads();

    int eloc = tid >> 1;
    int half = tid & 1;
    int e = blockIdx.x * 128 + eloc;
    int r = rowI[e], c = colI[e];

    float dx = pos[r * 3 + 0] - pos[c * 3 + 0];
    float dy = pos[r * 3 + 1] - pos[c * 3 + 1];
    float dz = pos[r * 3 + 2] - pos[c * 3 + 2];
    float dist = sqrtf(dx * dx + dy * dy + dz * dz);

    const unsigned short* f1 = F12 + (size_t)r * 128 + half * 64;
    const unsigned short* f2 = F12 + (size_t)NAP * 128 + (size_t)c * 128 + half * 64;
    const int jb = half * 64;

    float ps[3] = {0.0f, 0.0f, 0.0f};
#pragma unroll
    for (int blk = 0; blk < 8; blk++) {
        uint4 a = *(const uint4*)(f1 + blk * 8);
        uint4 b = *(const uint4*)(f2 + blk * 8);
        unsigned av[4] = {a.x, a.y, a.z, a.w};
        unsigned bvv[4] = {b.x, b.y, b.z, b.w};
#pragma unroll
        for (int q = 0; q < 4; q++) {
            int j0 = jb + blk * 8 + q * 2;
            float h0 = silu_f(bf2f((unsigned short)(av[q] & 0xFFFFu)) + bf2f((unsigned short)(bvv[q] & 0xFFFFu))
                              + dist * Wd[j0] + B1[j0]);
            float h1 = silu_f(bf2f((unsigned short)(av[q] >> 16)) + bf2f((unsigned short)(bvv[q] >> 16))
                              + dist * Wd[j0 + 1] + B1[j0 + 1]);
#pragma unroll
            for (int o = 0; o < 3; o++)
                ps[o] += h0 * W2s[j0 * 3 + o] + h1 * W2s[(j0 + 1) * 3 + o];
        }
    }
#pragma unroll
    for (int o = 0; o < 3; o++) ps[o] += __shfl_xor(ps[o], 1, 64);
    if (half == 0) {
#pragma unroll
        for (int o = 0; o < 3; o++) outS[(size_t)e * 3 + o] = ps[o] + b2[o];
    }
}

// ---------------- sort / scan -----------------------------------------------
__global__ void k_count_edges(const int* __restrict__ row, int* __restrict__ cnt) {
    int e = blockIdx.x * blockDim.x + threadIdx.x;
    if (e < NE) atomicAdd(&cnt[row[e]], 1);
}

__global__ void k_scan_block(const int* __restrict__ cnt, int* __restrict__ ptr,
                             int* __restrict__ btot) {
    __shared__ int s[256];
    int tid = threadIdx.x;
    int i = blockIdx.x * 256 + tid;
    int v = (i < NA) ? cnt[i] : 0;
    s[tid] = v;
    __syncthreads();
    for (int off = 1; off < 256; off <<= 1) {
        int t = (tid >= off) ? s[tid - off] : 0;
        __syncthreads();
        s[tid] += t;
        __syncthreads();
    }
    if (i < NA) ptr[i] = s[tid] - v;
    if (tid == 255) btot[blockIdx.x] = s[255];
}

__global__ void k_scan_tot(int* __restrict__ btot) {
    int lane = threadIdx.x;
    int v = (lane < NSB) ? btot[lane] : 0;
    int orig = v;
    for (int off = 1; off < 64; off <<= 1) {
        int t = __shfl_up(v, off, 64);
        if (lane >= off) v += t;
    }
    if (lane < NSB) btot[lane] = v - orig;
}

__global__ void k_scan_add(int* __restrict__ ptr, const int* __restrict__ btot) {
    int i = blockIdx.x * 256 + threadIdx.x;
    if (i < NA) ptr[i] += btot[i >> 8];
    if (i == 0) ptr[NA] = NE;
}

__global__ void k_copy_cursor(const int* __restrict__ ptr, int* __restrict__ cursor) {
    int i = blockIdx.x * 256 + threadIdx.x;
    if (i < NA) cursor[i] = ptr[i];
}

__global__ void k_sort(const int* __restrict__ row, const int* __restrict__ col,
                       int* __restrict__ cursor,
                       int* __restrict__ row_s, int* __restrict__ col_s) {
    int e = blockIdx.x * blockDim.x + threadIdx.x;
    if (e >= NE) return;
    int r = row[e];
    int p = atomicAdd(&cursor[r], 1);
    row_s[p] = r;
    col_s[p] = col[e];
}

__global__ void k_gptr(const int* __restrict__ bid, int* __restrict__ gptr) {
    int n = blockIdx.x * blockDim.x + threadIdx.x;
    if (n >= NA) return;
    int b = bid[n];
    int bp = (n == 0) ? -1 : bid[n - 1];
    for (int g = bp + 1; g <= b; g++) gptr[g] = n;
    if (n == NA - 1)
        for (int g = b + 1; g <= NG; g++) gptr[g] = NA;
}

// ---------------- misc small kernels ----------------------------------------
__global__ void k_init_feat(const int* __restrict__ atoms,
                            const float* __restrict__ emb,
                            float* __restrict__ feat, unsigned short* __restrict__ featb) {
    int idx = blockIdx.x * blockDim.x + threadIdx.x;
    if (idx >= NA * DF) return;
    float v = emb[atoms[idx >> 7] * DF + (idx & 127)];
    feat[idx] = v;
    featb[idx] = f2bf(v);
}

__global__ void k_copy_pos(const float* __restrict__ pos, float* __restrict__ posc) {
    int idx = blockIdx.x * blockDim.x + threadIdx.x;
    if (idx < NA * 3) posc[idx] = pos[idx];
}

__global__ void k_com_g(const float* __restrict__ pos, const int* __restrict__ gptr,
                        float* __restrict__ com) {
    int g = blockIdx.x;
    int lane = threadIdx.x;
    int s0 = gptr[g], s1 = gptr[g + 1];
    float sx = 0.0f, sy = 0.0f, sz = 0.0f;
    for (int n = s0 + lane; n < s1; n += 64) {
        sx += pos[n * 3 + 0];
        sy += pos[n * 3 + 1];
        sz += pos[n * 3 + 2];
    }
#pragma unroll
    for (int off = 32; off > 0; off >>= 1) {
        sx += __shfl_down(sx, off, 64);
        sy += __shfl_down(sy, off, 64);
        sz += __shfl_down(sz, off, 64);
    }
    if (lane == 0) {
        float cinv = 1.0f / fmaxf((float)(s1 - s0), 1.0f);
        com[g * 3 + 0] = sx * cinv;
        com[g * 3 + 1] = sy * cinv;
        com[g * 3 + 2] = sz * cinv;
    }
}

__global__ void k_gather_sph(const int* __restrict__ ptr, const int* __restrict__ col_s,
                             const float* __restrict__ pos, const float* __restrict__ msg,
                             float* __restrict__ sh_mean) {
    int n = blockIdx.x;
    int lane = threadIdx.x;
    int s0 = ptr[n], s1 = ptr[n + 1];
    float px = pos[n * 3 + 0], py = pos[n * 3 + 1], pz = pos[n * 3 + 2];
    float a[9];
#pragma unroll
    for (int j = 0; j < 9; j++) a[j] = 0.0f;
    for (int e = s0 + lane; e < s1; e += 64) {
        int c = col_s[e];
        float dx = px - pos[c * 3 + 0];
        float dy = py - pos[c * 3 + 1];
        float dz = pz - pos[c * 3 + 2];
        float s[9];
        sph9(dx, dy, dz, s);
        float w0 = msg[e * 3 + 0], w1 = msg[e * 3 + 1], w2 = msg[e * 3 + 2];
        a[0] += s[0] * w0;
        a[1] += s[1] * w1; a[2] += s[2] * w1; a[3] += s[3] * w1;
        a[4] += s[4] * w2; a[5] += s[5] * w2; a[6] += s[6] * w2;
        a[7] += s[7] * w2; a[8] += s[8] * w2;
    }
#pragma unroll
    for (int off = 32; off > 0; off >>= 1)
#pragma unroll
        for (int j = 0; j < 9; j++) a[j] += __shfl_down(a[j], off, 64);
    if (lane == 0) {
        float cinv = 1.0f / fmaxf((float)(s1 - s0), 1.0f);
#pragma unroll
        for (int j = 0; j < 9; j++) sh_mean[(size_t)n * 9 + j] = a[j] * cinv;
    }
}

__global__ void k_sh_finish(const float* __restrict__ sh_mean,
                            const float* __restrict__ pos, const float* __restrict__ com,
                            const int* __restrict__ bid, const float* __restrict__ msgC,
                            float* __restrict__ sh) {
    int n = blockIdx.x * blockDim.x + threadIdx.x;
    if (n >= NA) return;
    int b = bid[n];
    float dx = pos[n * 3 + 0] - com[b * 3 + 0];
    float dy = pos[n * 3 + 1] - com[b * 3 + 1];
    float dz = pos[n * 3 + 2] - com[b * 3 + 2];
    float s[9];
    sph9(dx, dy, dz, s);
    float w2 = msgC[n * 3 + 2];
    sh[n * 9 + 0] = 0.0f;
    sh[n * 9 + 1] = 0.0f;
    sh[n * 9 + 2] = 0.0f;
    sh[n * 9 + 3] = 0.0f;
#pragma unroll
    for (int j = 4; j < 9; j++)
        sh[n * 9 + j] = sh_mean[(size_t)n * 9 + j] + s[j] * w2;
}

// fused per-node gather: Xn build (all 128 threads) + p/s aggregation + update
__global__ __launch_bounds__(128) void k_gather_nx(
    const int* __restrict__ ptr, const int* __restrict__ col_s,
    const unsigned short* __restrict__ bufMb, const unsigned short* __restrict__ featb,
    const float* __restrict__ pos, const float* __restrict__ sh,
    const float* __restrict__ psc, const float* __restrict__ ssc,
    unsigned short* __restrict__ Xnb,
    float* __restrict__ pos_new, float* __restrict__ sh_new)
{
    int n = blockIdx.x;
    int tid = threadIdx.x;
    int s0 = ptr[n], s1 = ptr[n + 1];
    float cinv = 1.0f / fmaxf((float)(s1 - s0), 1.0f);

    float sum = 0.0f;
    for (int e = s0; e < s1; e++) sum += bf2f(bufMb[(size_t)e * 128 + tid]);
    Xnb[(size_t)n * 256 + tid] = featb[(size_t)n * 128 + tid];
    Xnb[(size_t)n * 256 + 128 + tid] = f2bf(sum * cinv);

    if (tid < 64) {
        int lane = tid;
        float px = pos[n * 3 + 0], py = pos[n * 3 + 1], pz = pos[n * 3 + 2];
        float shn[9];
#pragma unroll
        for (int j = 0; j < 9; j++) shn[j] = sh[(size_t)n * 9 + j];
        float a[12];
#pragma unroll
        for (int j = 0; j < 12; j++) a[j] = 0.0f;
        for (int e = s0 + lane; e < s1; e += 64) {
            int c = col_s[e];
            float p = psc[e];
            a[0] += (px - pos[c * 3 + 0]) * p;
            a[1] += (py - pos[c * 3 + 1]) * p;
            a[2] += (pz - pos[c * 3 + 2]) * p;
            float w0 = ssc[e * 3 + 0], w1 = ssc[e * 3 + 1], w2 = ssc[e * 3 + 2];
            const float* sc = sh + (size_t)c * 9;
            a[3]  += (shn[0] - sc[0]) * w0;
            a[4]  += (shn[1] - sc[1]) * w1;
            a[5]  += (shn[2] - sc[2]) * w1;
            a[6]  += (shn[3] - sc[3]) * w1;
            a[7]  += (shn[4] - sc[4]) * w2;
            a[8]  += (shn[5] - sc[5]) * w2;
            a[9]  += (shn[6] - sc[6]) * w2;
            a[10] += (shn[7] - sc[7]) * w2;
            a[11] += (shn[8] - sc[8]) * w2;
        }
#pragma unroll
        for (int off = 32; off > 0; off >>= 1)
#pragma unroll
            for (int j = 0; j < 12; j++) a[j] += __shfl_down(a[j], off, 64);
        if (lane == 0) {
            pos_new[n * 3 + 0] = px + a[0] * cinv;
            pos_new[n * 3 + 1] = py + a[1] * cinv;
            pos_new[n * 3 + 2] = pz + a[2] * cinv;
#pragma unroll
            for (int j = 0; j < 9; j++) sh_new[(size_t)n * 9 + j] = shn[j] + a[3 + j] * cinv;
        }
    }
}

__global__ __launch_bounds__(192) void k_pool_pred(
    const int* __restrict__ gptr, const float* __restrict__ feat,
    const float* __restrict__ pos, const float* __restrict__ sh,
    const float* __restrict__ Wp, const float* __restrict__ bp,
    float* __restrict__ out) {
    __shared__ float pl[140];
    int g = blockIdx.x;
    int c = threadIdx.x;
    int s0 = gptr[g], s1 = gptr[g + 1];
    if (c < 140) {
        float sum = 0.0f;
        for (int n = s0; n < s1; n++) {
            float v;
            if (c < 128)      v = feat[(size_t)n * 128 + c];
            else if (c < 131) v = pos[n * 3 + (c - 128)];
            else              v = sh[(size_t)n * 9 + (c - 131)];
            sum += v;
        }
        pl[c] = sum;
    }
    __syncthreads();
    if (c < 64) {
        float s = 0.0f;
        for (int k = c; k < 140; k += 64) s += pl[k] * Wp[k];
#pragma unroll
        for (int off = 32; off > 0; off >>= 1) s += __shfl_down(s, off, 64);
        if (c == 0) out[g] = s + bp[0];
    }
}

// ---------------------------------------------------------------------------
extern "C" void kernel_launch(void* const* d_in, const int* in_sizes, int n_in,
                              void* d_out, int out_size, void* d_ws, size_t ws_size,
                              hipStream_t stream) {
    const int*   atoms  = (const int*)d_in[0];
    const int*   eidx   = (const int*)d_in[1];
    const int*   row    = eidx;
    const int*   col    = eidx + NE;
    const int*   bid    = (const int*)d_in[2];
    const float* pos_in = (const float*)d_in[3];
    const float* emb    = (const float*)d_in[4];
    const float* Wsi1   = (const float*)d_in[5];
    const float* bsi1   = (const float*)d_in[6];
    const float* Wsi2   = (const float*)d_in[7];
    const float* bsi2   = (const float*)d_in[8];
    const float* WsiC1  = (const float*)d_in[9];
    const float* bsiC1  = (const float*)d_in[10];
    const float* WsiC2  = (const float*)d_in[11];
    const float* bsiC2  = (const float*)d_in[12];
    const float* Wm1    = (const float*)d_in[13];
    const float* bm1    = (const float*)d_in[14];
    const float* Wm2    = (const float*)d_in[15];
    const float* bm2    = (const float*)d_in[16];
    const float* Wp1    = (const float*)d_in[17];
    const float* bp1    = (const float*)d_in[18];
    const float* Wp2    = (const float*)d_in[19];
    const float* bp2    = (const float*)d_in[20];
    const float* Wn1    = (const float*)d_in[21];
    const float* bn1    = (const float*)d_in[22];
    const float* Wn2    = (const float*)d_in[23];
    const float* bn2    = (const float*)d_in[24];
    const float* Ws1    = (const float*)d_in[25];
    const float* bs1    = (const float*)d_in[26];
    const float* Ws2    = (const float*)d_in[27];
    const float* bs2    = (const float*)d_in[28];
    const float* Wpred  = (const float*)d_in[29];
    const float* bpred  = (const float*)d_in[30];

    float* base = (float*)d_ws;
    size_t off = 0;
    auto alloc = [&](size_t nfl) { float* r = base + off; off += nfl; return r; };
    unsigned short* bufMb = (unsigned short*)alloc((size_t)NE * DF / 2);
    unsigned short* featb = (unsigned short*)alloc((size_t)NAP * DF / 2);
    unsigned short* hnb   = (unsigned short*)alloc((size_t)NAP * DF / 2);
    unsigned short* Xnb   = (unsigned short*)alloc((size_t)NAP * 256 / 2);
    unsigned short* F12   = (unsigned short*)alloc((size_t)NAP * 256 / 2);
    unsigned short* WT    = (unsigned short*)alloc(WT_TOTAL / 2);
    float* feat    = alloc((size_t)NAP * DF);
    float* sc3     = alloc((size_t)NE * 3);
    float* psc     = alloc(NE);
    float* pos0    = alloc((size_t)NA * 3 + 4);
    float* pos1    = alloc((size_t)NA * 3 + 4);
    float* sh0     = alloc((size_t)NA * 9 + 4);
    float* sh1     = alloc((size_t)NA * 9 + 4);
    float* sh_mean = alloc((size_t)NA * 9 + 4);
    float* com     = alloc(NG * 3 + 4);
    float* msgC    = alloc((size_t)NA * 3 + 4);
    int* cnt_row   = (int*)alloc(NA);
    int* ptr       = (int*)alloc(NA + 4);
    int* cursor    = (int*)alloc(NA);
    int* gptr      = (int*)alloc(NG + 4);
    int* row_s     = (int*)alloc(NE);
    int* col_s     = (int*)alloc(NE);
    int* btot      = (int*)alloc(64);

    const dim3 B256(256);
    const int gE = NE / 128;                    // 1250
    const int gN = NAP / 128;                   // 79
    const dim3 gF(gN, 2);

    // ---------- setup: weights, sort, graph ranges ----------
    hipMemsetAsync(cnt_row, 0, NA * sizeof(int), stream);
    k_prep_w<<<(WT_TOTAL + 255) / 256, B256, 0, stream>>>(Wsi1, WsiC1, Wm1, Wm2, Wp1, Ws1, Wn1, Wn2, WT);
    k_init_feat<<<(NA * DF + 255) / 256, B256, 0, stream>>>(atoms, emb, feat, featb);
    k_copy_pos<<<(NA * 3 + 255) / 256, B256, 0, stream>>>(pos_in, pos0);
    k_count_edges<<<(NE + 255) / 256, B256, 0, stream>>>(row, cnt_row);
    k_scan_block<<<NSB, B256, 0, stream>>>(cnt_row, ptr, btot);
    k_scan_tot<<<1, 64, 0, stream>>>(btot);
    k_scan_add<<<NSB, B256, 0, stream>>>(ptr, btot);
    k_copy_cursor<<<NSB, B256, 0, stream>>>(ptr, cursor);
    k_sort<<<(NE + 255) / 256, B256, 0, stream>>>(row, col, cursor, row_s, col_s);
    k_gptr<<<(NA + 255) / 256, B256, 0, stream>>>(bid, gptr);
    k_com_g<<<NG, 64, 0, stream>>>(pos_in, gptr, com);

    // ---------- initial sh ----------
    k_fgemm<<<gF, B256, 0, stream>>>(featb, WT + OFF_SIRC, F12);
    k_edge_si<<<gE, B256, 0, stream>>>(row_s, col_s, F12, pos0, Wsi1, bsi1, Wsi2, bsi2, sc3);
    k_gather_sph<<<NA, 64, 0, stream>>>(ptr, col_s, pos0, sc3, sh_mean);
    gemm_mfma<128, true, 3, false><<<gN, B256, 0, stream>>>(
        featb, WT + OFF_SICTR, bsiC1, NA, nullptr, nullptr, WsiC2, bsiC2, msgC);
    k_sh_finish<<<(NA + 255) / 256, B256, 0, stream>>>(sh_mean, pos0, com, bid, msgC, sh0);

    float* posA = pos0; float* posB = pos1;
    float* shA = sh0;   float* shB = sh1;

    // ---------- layers ----------
    for (int l = 0; l < NL; l++) {
        const unsigned short* wtL = WT + LBASE + (size_t)l * LSIZE;
        const float* cm1 = bm1 + l * 128;
        const float* wtail = Wm1 + (size_t)l * 33280 + 256 * 128;  // rows 256..259
        const float* cm2 = bm2 + l * 128;
        const float* cp1 = bp1 + l * 128;
        const float* wp2 = Wp2 + (size_t)l * 128;
        const float* cp2 = bp2 + l;
        const float* cn1 = bn1 + l * 128;
        const float* cn2 = bn2 + l * 128;
        const float* cs1 = bs1 + l * 128;
        const float* ws2 = Ws2 + (size_t)l * 128 * 3;
        const float* cs2 = bs2 + l * 3;

        k_fgemm<<<gF, B256, 0, stream>>>(featb, wtL + LOFF_MRC, F12);
        k_m2f<<<gE, B256, 0, stream>>>(
            row_s, col_s, F12, posA, shA, wtail, cm1, wtL + LOFF_M2, cm2, bufMb);
        gemm_mfma<128, true, 1, false><<<gE, B256, 0, stream>>>(
            bufMb, wtL + LOFF_P1, cp1, NE, nullptr, nullptr, wp2, cp2, psc);
        gemm_mfma<128, true, 3, false><<<gE, B256, 0, stream>>>(
            bufMb, wtL + LOFF_S1, cs1, NE, nullptr, nullptr, ws2, cs2, sc3);
        k_gather_nx<<<NA, 128, 0, stream>>>(ptr, col_s, bufMb, featb, posA, shA, psc, sc3,
                                            Xnb, posB, shB);
        gemm_mfma<256, true, 0, false><<<gN, B256, 0, stream>>>(
            Xnb, wtL + LOFF_N1, cn1, NA, hnb, nullptr, nullptr, nullptr, nullptr);
        gemm_mfma<128, false, 0, true><<<gN, B256, 0, stream>>>(
            hnb, wtL + LOFF_N2, cn2, NA, featb, feat, nullptr, nullptr, nullptr);

        float* tp = posA; posA = posB; posB = tp;
        float* ts = shA;  shA = shB;  shB = ts;
    }

    // ---------- pooling + prediction ----------
    k_pool_pred<<<NG, 192, 0, stream>>>(gptr, feat, posA, shA, Wpred, bpred, (float*)d_out);
}

// Round 12
// 949.050 us; speedup vs baseline: 1.0479x; 1.0479x over previous
//
#include <hip/hip_runtime.h>
#include <math.h>

#define NA 10000      // atoms
#define NE 160000     // edges
#define NG 100        // graphs
#define DF 128
#define NL 5
#define NAP 10112     // NA padded to 128-row tiles (79*128)
#define NSB 40        // scan blocks = ceil(NA/256)

typedef __attribute__((ext_vector_type(8))) short bfx8;
typedef __attribute__((ext_vector_type(4))) float f32x4;

__device__ __forceinline__ float silu_f(float x) {
    return x / (1.0f + __expf(-x));
}

__device__ __forceinline__ unsigned short f2bf(float x) {
    unsigned u = __builtin_bit_cast(unsigned, x);
    u = (u + 0x7FFFu + ((u >> 16) & 1u)) >> 16;
    return (unsigned short)u;
}
__device__ __forceinline__ float bf2f(unsigned short h) {
    unsigned u = ((unsigned)h) << 16;
    return __builtin_bit_cast(float, u);
}
__device__ __forceinline__ unsigned packbf(float lo, float hi) {
    return (unsigned)f2bf(lo) | ((unsigned)f2bf(hi) << 16);
}

__device__ __forceinline__ void sph9(float dx, float dy, float dz, float* s) {
    float r = sqrtf(dx * dx + dy * dy + dz * dz);
    float inv = 1.0f / fmaxf(r, 1e-12f);
    float x = dx * inv, y = dy * inv, z = dz * inv;
    const float S3 = 1.7320508075688772f;
    s[0] = 1.0f;
    s[1] = x; s[2] = y; s[3] = z;
    s[4] = S3 * x * z;
    s[5] = S3 * x * y;
    s[6] = y * y - 0.5f * (x * x + z * z);
    s[7] = S3 * y * z;
    s[8] = 0.5f * S3 * (z * z - x * x);
}

// ---------------- weight prep: transpose + bf16 ------------------------------
#define OFF_SIRC  0        // si1 pair [2][128][128]
#define OFF_SICTR 32768    // siC1 [128][128]
#define LBASE     49152
#define LOFF_MRC  0        // m1 pair [2][128][128]
#define LOFF_M2   32768
#define LOFF_P1   49152
#define LOFF_S1   65536
#define LOFF_N1   81920    // [128][256]
#define LOFF_N2   114688
#define LSIZE     131072
#define WT_TOTAL  704512   // 49152 + 5*131072

__global__ void k_prep_w(const float* __restrict__ Wsi1, const float* __restrict__ WsiC1,
                         const float* __restrict__ Wm1, const float* __restrict__ Wm2,
                         const float* __restrict__ Wp1, const float* __restrict__ Ws1,
                         const float* __restrict__ Wn1, const float* __restrict__ Wn2,
                         unsigned short* __restrict__ WT) {
    int flat = blockIdx.x * 256 + threadIdx.x;
    if (flat >= WT_TOTAL) return;
    float v = 0.0f;
    if (flat < OFF_SICTR) {                      // si1 pair: rows 1..128 / 129..256
        int half = flat >> 14;
        int o = flat & 16383;
        int n = o >> 7, k = o & 127;
        v = Wsi1[(k + 1 + half * 128) * 128 + n];
    } else if (flat < LBASE) {                   // siC1
        int o = flat - OFF_SICTR;
        int n = o >> 7, k = o & 127;
        v = WsiC1[k * 128 + n];
    } else {
        int t = flat - LBASE;
        int lyr = t / LSIZE;
        int o = t % LSIZE;
        if (o < LOFF_M2) {                       // m1 pair
            int half = o >> 14;
            int o2 = o & 16383;
            int n = o2 >> 7, k = o2 & 127;
            v = Wm1[(size_t)lyr * 33280 + (k + half * 128) * 128 + n];
        } else if (o < LOFF_P1) {
            int o2 = o - LOFF_M2; int n = o2 >> 7, k = o2 & 127;
            v = Wm2[(size_t)lyr * 16384 + k * 128 + n];
        } else if (o < LOFF_S1) {
            int o2 = o - LOFF_P1; int n = o2 >> 7, k = o2 & 127;
            v = Wp1[(size_t)lyr * 16384 + k * 128 + n];
        } else if (o < LOFF_N1) {
            int o2 = o - LOFF_S1; int n = o2 >> 7, k = o2 & 127;
            v = Ws1[(size_t)lyr * 16384 + k * 128 + n];
        } else if (o < LOFF_N2) {
            int o2 = o - LOFF_N1; int n = o2 >> 8, k = o2 & 255;
            v = Wn1[(size_t)lyr * 32768 + k * 128 + n];
        } else {
            int o2 = o - LOFF_N2; int n = o2 >> 7, k = o2 & 127;
            v = Wn2[(size_t)lyr * 16384 + k * 128 + n];
        }
    }
    WT[flat] = f2bf(v);
}

// ---------------- F-pair node GEMM: F12[y] = featb @ WT2[y]  (no bias/act) ---
__global__ __launch_bounds__(256) void k_fgemm(
    const unsigned short* __restrict__ Ab,    // featb [NAP][128]
    const unsigned short* __restrict__ WT2,   // [2][128][128]
    unsigned short* __restrict__ F12)         // [2][NAP][128]
{
    __shared__ unsigned short As[128 * 40];
    __shared__ unsigned short Bs[128 * 40];
    const unsigned short* WTp = WT2 + (size_t)blockIdx.y * 16384;
    unsigned short* Cb = F12 + (size_t)blockIdx.y * NAP * 128;

    const int tid = threadIdx.x;
    const int m0 = blockIdx.x * 128;
    const int mlo = tid >> 2;
    const int part = tid & 3;
    const int w = tid >> 6, l = tid & 63;
    const int quad = l >> 4, lm = l & 15;
    const int wm = (w >> 1) * 64, wn = (w & 1) * 64;

    f32x4 acc[4][4] = {};
#pragma unroll 1
    for (int c = 0; c < 4; c++) {
        const int k0 = c * 32;
#pragma unroll
        for (int i = 0; i < 2; i++) {
            const int m = mlo + i * 64;
            *(uint4*)&As[m * 40 + part * 8] =
                *(const uint4*)(Ab + (size_t)(m0 + m) * 128 + k0 + part * 8);
            *(uint4*)&Bs[m * 40 + part * 8] =
                *(const uint4*)(WTp + (size_t)m * 128 + k0 + part * 8);
        }
        __syncthreads();
        bfx8 a[4], b[4];
#pragma unroll
        for (int i = 0; i < 4; i++) a[i] = *(const bfx8*)&As[(wm + i * 16 + lm) * 40 + quad * 8];
#pragma unroll
        for (int j = 0; j < 4; j++) b[j] = *(const bfx8*)&Bs[(wn + j * 16 + lm) * 40 + quad * 8];
#pragma unroll
        for (int i = 0; i < 4; i++)
#pragma unroll
            for (int j = 0; j < 4; j++)
                acc[i][j] = __builtin_amdgcn_mfma_f32_16x16x32_bf16(a[i], b[j], acc[i][j], 0, 0, 0);
        __syncthreads();
    }
#pragma unroll
    for (int i = 0; i < 4; i++) {
        const int rbase = wm + i * 16 + quad * 4;
#pragma unroll
        for (int r = 0; r < 4; r++) {
            const int e = m0 + rbase + r;
#pragma unroll
            for (int j = 0; j < 4; j++)
                Cb[(size_t)e * 128 + wn + j * 16 + lm] = f2bf(acc[i][j][r]);
        }
    }
}

// ---------------- LDS-staged MFMA GEMM (R8 structure) ------------------------
template <int KP, bool ACT, int NOUT, bool F32OUT>
__global__ __launch_bounds__(256) void gemm_mfma(
    const unsigned short* __restrict__ Ab,
    const unsigned short* __restrict__ WT,
    const float* __restrict__ bias, int M,
    unsigned short* __restrict__ Cb, float* __restrict__ Cf,
    const float* __restrict__ W2, const float* __restrict__ b2,
    float* __restrict__ outS)
{
    constexpr int NO = (NOUT > 0) ? NOUT : 1;
    __shared__ unsigned short As[128 * 40];
    __shared__ unsigned short Bs[128 * 40];
    __shared__ float W2s[NOUT > 0 ? 128 * NO : 1];
    __shared__ float red[NOUT > 0 ? 128 * 8 * NO : 1];

    const int tid = threadIdx.x;
    const int m0 = blockIdx.x * 128;
    const int mlo = tid >> 2;
    const int part = tid & 3;

    if (NOUT > 0) {
        for (int t = tid; t < 128 * NO; t += 256) W2s[t] = W2[t];
    }

    const int w = tid >> 6, l = tid & 63;
    const int quad = l >> 4, lm = l & 15;
    const int wm = (w >> 1) * 64, wn = (w & 1) * 64;

    float bv[4];
#pragma unroll
    for (int j = 0; j < 4; j++) bv[j] = bias[wn + j * 16 + lm];

    f32x4 acc[4][4] = {};
    constexpr int NCH = KP / 32;
#pragma unroll 1
    for (int c = 0; c < NCH; c++) {
        const int k0 = c * 32;
#pragma unroll
        for (int i = 0; i < 2; i++) {
            const int m = mlo + i * 64;
            *(uint4*)&As[m * 40 + part * 8] =
                *(const uint4*)(Ab + (size_t)(m0 + m) * KP + k0 + part * 8);
            *(uint4*)&Bs[m * 40 + part * 8] =
                *(const uint4*)(WT + (size_t)m * KP + k0 + part * 8);
        }
        __syncthreads();
        bfx8 a[4], b[4];
#pragma unroll
        for (int i = 0; i < 4; i++) a[i] = *(const bfx8*)&As[(wm + i * 16 + lm) * 40 + quad * 8];
#pragma unroll
        for (int j = 0; j < 4; j++) b[j] = *(const bfx8*)&Bs[(wn + j * 16 + lm) * 40 + quad * 8];
#pragma unroll
        for (int i = 0; i < 4; i++)
#pragma unroll
            for (int j = 0; j < 4; j++)
                acc[i][j] = __builtin_amdgcn_mfma_f32_16x16x32_bf16(a[i], b[j], acc[i][j], 0, 0, 0);
        __syncthreads();
    }

    if (NOUT > 0) {
        const int slot = (w & 1) * 4 + (lm >> 2);
#pragma unroll
        for (int i = 0; i < 4; i++) {
#pragma unroll
            for (int r = 0; r < 4; r++) {
                const int rowL = wm + i * 16 + quad * 4 + r;
                float ps[NO];
#pragma unroll
                for (int o = 0; o < NO; o++) ps[o] = 0.0f;
#pragma unroll
                for (int j = 0; j < 4; j++) {
                    float v = silu_f(acc[i][j][r] + bv[j]);
                    const int colg = wn + j * 16 + lm;
#pragma unroll
                    for (int o = 0; o < NO; o++) ps[o] += v * W2s[colg * NO + o];
                }
#pragma unroll
                for (int off = 1; off <= 2; off <<= 1)
#pragma unroll
                    for (int o = 0; o < NO; o++) ps[o] += __shfl_xor(ps[o], off, 64);
                if ((lm & 3) == 0)
#pragma unroll
                    for (int o = 0; o < NO; o++)
                        red[(rowL * 8 + slot) * NO + o] = ps[o];
            }
        }
        __syncthreads();
        for (int t = tid; t < 128 * NO; t += 256) {
            int rowL = t / NO, o = t - rowL * NO;
            float s = 0.0f;
#pragma unroll
            for (int k = 0; k < 8; k++) s += red[(rowL * 8 + k) * NO + o];
            int e = m0 + rowL;
            if (e < M) outS[(size_t)e * NO + o] = s + b2[o];
        }
    } else {
#pragma unroll
        for (int i = 0; i < 4; i++) {
            const int rbase = wm + i * 16 + quad * 4;
#pragma unroll
            for (int r = 0; r < 4; r++) {
                const int e = m0 + rbase + r;
                if (e >= M) continue;
#pragma unroll
                for (int j = 0; j < 4; j++) {
                    float v = acc[i][j][r] + bv[j];
                    if (ACT) v = silu_f(v);
                    const int colg = wn + j * 16 + lm;
                    Cb[(size_t)e * 128 + colg] = f2bf(v);
                    if (F32OUT) Cf[(size_t)e * 128 + colg] = v;
                }
            }
        }
    }
}

// ---------------- streaming edge kernel (layers), coalesced-write version ----
// 8 threads per edge; grid = NE/32. Writes: 2x uint4/thread, wave covers
// 8 edges x 128B fully contiguous per store -> no partial 64B sectors.
__global__ __launch_bounds__(256) void k_edge_h(
    const int* __restrict__ rowI, const int* __restrict__ colI,
    const unsigned short* __restrict__ F12,    // [2][NAP][128]
    const float* __restrict__ pos, const float* __restrict__ sh,
    const float* __restrict__ wtail,           // [4][128] fp32 (Wm1 rows 256..259)
    const float* __restrict__ b1,
    unsigned short* __restrict__ bufHb)
{
    __shared__ float Wt[4][128];
    __shared__ float B1[128];
    int tid = threadIdx.x;
    if (tid < 128) B1[tid] = b1[tid];
    for (int t = tid; t < 512; t += 256) Wt[t >> 7][t & 127] = wtail[t];
    __syncthreads();

    const int e = blockIdx.x * 32 + (tid >> 3);
    const int sub = tid & 7;
    const int l = tid & 63;
    const int r = rowI[e], c = colI[e];

    float d2 = 0.0f, ip0 = 0.0f, ip1 = 0.0f, ip2 = 0.0f;
    if (sub == 0) {
        float dx = pos[r * 3 + 0] - pos[c * 3 + 0];
        float dy = pos[r * 3 + 1] - pos[c * 3 + 1];
        float dz = pos[r * 3 + 2] - pos[c * 3 + 2];
        d2 = dx * dx + dy * dy + dz * dz;
        const float* sr = sh + (size_t)r * 9;
        const float* sc = sh + (size_t)c * 9;
        ip0 = sr[0] * sc[0];
        ip1 = sr[1] * sc[1] + sr[2] * sc[2] + sr[3] * sc[3];
        ip2 = sr[4] * sc[4] + sr[5] * sc[5] + sr[6] * sc[6] + sr[7] * sc[7] + sr[8] * sc[8];
    }
    const int src = l & ~7;
    d2  = __shfl(d2,  src, 64);
    ip0 = __shfl(ip0, src, 64);
    ip1 = __shfl(ip1, src, 64);
    ip2 = __shfl(ip2, src, 64);

    const unsigned short* f1 = F12 + (size_t)r * 128;
    const unsigned short* f2 = F12 + (size_t)NAP * 128 + (size_t)c * 128;
    unsigned short* outp = bufHb + (size_t)e * 128;

#pragma unroll
    for (int hc = 0; hc < 2; hc++) {
        const int j0b = hc * 64 + sub * 8;
        uint4 a = *(const uint4*)(f1 + j0b);
        uint4 b = *(const uint4*)(f2 + j0b);
        unsigned av[4] = {a.x, a.y, a.z, a.w};
        unsigned bvv[4] = {b.x, b.y, b.z, b.w};
        unsigned ov[4];
#pragma unroll
        for (int q = 0; q < 4; q++) {
            int j0 = j0b + q * 2;
            float h0 = bf2f((unsigned short)(av[q] & 0xFFFFu)) + bf2f((unsigned short)(bvv[q] & 0xFFFFu))
                     + d2 * Wt[0][j0] + ip0 * Wt[1][j0] + ip1 * Wt[2][j0] + ip2 * Wt[3][j0] + B1[j0];
            float h1 = bf2f((unsigned short)(av[q] >> 16)) + bf2f((unsigned short)(bvv[q] >> 16))
                     + d2 * Wt[0][j0 + 1] + ip0 * Wt[1][j0 + 1] + ip1 * Wt[2][j0 + 1] + ip2 * Wt[3][j0 + 1] + B1[j0 + 1];
            ov[q] = packbf(silu_f(h0), silu_f(h1));
        }
        *(uint4*)(outp + j0b) = make_uint4(ov[0], ov[1], ov[2], ov[3]);
    }
}

// ---------------- streaming edge kernel (init si) ----------------------------
__global__ __launch_bounds__(256) void k_edge_si(
    const int* __restrict__ rowI, const int* __restrict__ colI,
    const unsigned short* __restrict__ F12,    // [2][NAP][128]
    const float* __restrict__ pos,
    const float* __restrict__ Wsi1,            // row 0 = dist weights [128]
    const float* __restrict__ b1,
    const float* __restrict__ W2,              // [128][3]
    const float* __restrict__ b2,
    float* __restrict__ outS)                  // [NE][3]
{
    __shared__ float Wd[128];
    __shared__ float B1[128];
    __shared__ float W2s[128 * 3];
    int tid = threadIdx.x;
    if (tid < 128) { Wd[tid] = Wsi1[tid]; B1[tid] = b1[tid]; }
    for (int t = tid; t < 384; t += 256) W2s[t] = W2[t];
    __syncthreads();

    int eloc = tid >> 1;
    int half = tid & 1;
    int e = blockIdx.x * 128 + eloc;
    int r = rowI[e], c = colI[e];

    float dx = pos[r * 3 + 0] - pos[c * 3 + 0];
    float dy = pos[r * 3 + 1] - pos[c * 3 + 1];
    float dz = pos[r * 3 + 2] - pos[c * 3 + 2];
    float dist = sqrtf(dx * dx + dy * dy + dz * dz);

    const unsigned short* f1 = F12 + (size_t)r * 128 + half * 64;
    const unsigned short* f2 = F12 + (size_t)NAP * 128 + (size_t)c * 128 + half * 64;
    const int jb = half * 64;

    float ps[3] = {0.0f, 0.0f, 0.0f};
#pragma unroll
    for (int blk = 0; blk < 8; blk++) {
        uint4 a = *(const uint4*)(f1 + blk * 8);
        uint4 b = *(const uint4*)(f2 + blk * 8);
        unsigned av[4] = {a.x, a.y, a.z, a.w};
        unsigned bvv[4] = {b.x, b.y, b.z, b.w};
#pragma unroll
        for (int q = 0; q < 4; q++) {
            int j0 = jb + blk * 8 + q * 2;
            float h0 = silu_f(bf2f((unsigned short)(av[q] & 0xFFFFu)) + bf2f((unsigned short)(bvv[q] & 0xFFFFu))
                              + dist * Wd[j0] + B1[j0]);
            float h1 = silu_f(bf2f((unsigned short)(av[q] >> 16)) + bf2f((unsigned short)(bvv[q] >> 16))
                              + dist * Wd[j0 + 1] + B1[j0 + 1]);
#pragma unroll
            for (int o = 0; o < 3; o++)
                ps[o] += h0 * W2s[j0 * 3 + o] + h1 * W2s[(j0 + 1) * 3 + o];
        }
    }
#pragma unroll
    for (int o = 0; o < 3; o++) ps[o] += __shfl_xor(ps[o], 1, 64);
    if (half == 0) {
#pragma unroll
        for (int o = 0; o < 3; o++) outS[(size_t)e * 3 + o] = ps[o] + b2[o];
    }
}

// ---------------- sort / scan -----------------------------------------------
__global__ void k_count_edges(const int* __restrict__ row, int* __restrict__ cnt) {
    int e = blockIdx.x * blockDim.x + threadIdx.x;
    if (e < NE) atomicAdd(&cnt[row[e]], 1);
}

__global__ void k_scan_block(const int* __restrict__ cnt, int* __restrict__ ptr,
                             int* __restrict__ btot) {
    __shared__ int s[256];
    int tid = threadIdx.x;
    int i = blockIdx.x * 256 + tid;
    int v = (i < NA) ? cnt[i] : 0;
    s[tid] = v;
    __syncthreads();
    for (int off = 1; off < 256; off <<= 1) {
        int t = (tid >= off) ? s[tid - off] : 0;
        __syncthreads();
        s[tid] += t;
        __syncthreads();
    }
    if (i < NA) ptr[i] = s[tid] - v;
    if (tid == 255) btot[blockIdx.x] = s[255];
}

__global__ void k_scan_tot(int* __restrict__ btot) {
    int lane = threadIdx.x;
    int v = (lane < NSB) ? btot[lane] : 0;
    int orig = v;
    for (int off = 1; off < 64; off <<= 1) {
        int t = __shfl_up(v, off, 64);
        if (lane >= off) v += t;
    }
    if (lane < NSB) btot[lane] = v - orig;
}

__global__ void k_scan_add(int* __restrict__ ptr, const int* __restrict__ btot) {
    int i = blockIdx.x * 256 + threadIdx.x;
    if (i < NA) ptr[i] += btot[i >> 8];
    if (i == 0) ptr[NA] = NE;
}

__global__ void k_copy_cursor(const int* __restrict__ ptr, int* __restrict__ cursor) {
    int i = blockIdx.x * 256 + threadIdx.x;
    if (i < NA) cursor[i] = ptr[i];
}

__global__ void k_sort(const int* __restrict__ row, const int* __restrict__ col,
                       int* __restrict__ cursor,
                       int* __restrict__ row_s, int* __restrict__ col_s) {
    int e = blockIdx.x * blockDim.x + threadIdx.x;
    if (e >= NE) return;
    int r = row[e];
    int p = atomicAdd(&cursor[r], 1);
    row_s[p] = r;
    col_s[p] = col[e];
}

__global__ void k_gptr(const int* __restrict__ bid, int* __restrict__ gptr) {
    int n = blockIdx.x * blockDim.x + threadIdx.x;
    if (n >= NA) return;
    int b = bid[n];
    int bp = (n == 0) ? -1 : bid[n - 1];
    for (int g = bp + 1; g <= b; g++) gptr[g] = n;
    if (n == NA - 1)
        for (int g = b + 1; g <= NG; g++) gptr[g] = NA;
}

// ---------------- misc small kernels ----------------------------------------
__global__ void k_init_feat(const int* __restrict__ atoms,
                            const float* __restrict__ emb,
                            float* __restrict__ feat, unsigned short* __restrict__ featb) {
    int idx = blockIdx.x * blockDim.x + threadIdx.x;
    if (idx >= NA * DF) return;
    float v = emb[atoms[idx >> 7] * DF + (idx & 127)];
    feat[idx] = v;
    featb[idx] = f2bf(v);
}

__global__ void k_copy_pos(const float* __restrict__ pos, float* __restrict__ posc) {
    int idx = blockIdx.x * blockDim.x + threadIdx.x;
    if (idx < NA * 3) posc[idx] = pos[idx];
}

__global__ void k_com_g(const float* __restrict__ pos, const int* __restrict__ gptr,
                        float* __restrict__ com) {
    int g = blockIdx.x;
    int lane = threadIdx.x;
    int s0 = gptr[g], s1 = gptr[g + 1];
    float sx = 0.0f, sy = 0.0f, sz = 0.0f;
    for (int n = s0 + lane; n < s1; n += 64) {
        sx += pos[n * 3 + 0];
        sy += pos[n * 3 + 1];
        sz += pos[n * 3 + 2];
    }
#pragma unroll
    for (int off = 32; off > 0; off >>= 1) {
        sx += __shfl_down(sx, off, 64);
        sy += __shfl_down(sy, off, 64);
        sz += __shfl_down(sz, off, 64);
    }
    if (lane == 0) {
        float cinv = 1.0f / fmaxf((float)(s1 - s0), 1.0f);
        com[g * 3 + 0] = sx * cinv;
        com[g * 3 + 1] = sy * cinv;
        com[g * 3 + 2] = sz * cinv;
    }
}

__global__ void k_gather_sph(const int* __restrict__ ptr, const int* __restrict__ col_s,
                             const float* __restrict__ pos, const float* __restrict__ msg,
                             float* __restrict__ sh_mean) {
    int n = blockIdx.x;
    int lane = threadIdx.x;
    int s0 = ptr[n], s1 = ptr[n + 1];
    float px = pos[n * 3 + 0], py = pos[n * 3 + 1], pz = pos[n * 3 + 2];
    float a[9];
#pragma unroll
    for (int j = 0; j < 9; j++) a[j] = 0.0f;
    for (int e = s0 + lane; e < s1; e += 64) {
        int c = col_s[e];
        float dx = px - pos[c * 3 + 0];
        float dy = py - pos[c * 3 + 1];
        float dz = pz - pos[c * 3 + 2];
        float s[9];
        sph9(dx, dy, dz, s);
        float w0 = msg[e * 3 + 0], w1 = msg[e * 3 + 1], w2 = msg[e * 3 + 2];
        a[0] += s[0] * w0;
        a[1] += s[1] * w1; a[2] += s[2] * w1; a[3] += s[3] * w1;
        a[4] += s[4] * w2; a[5] += s[5] * w2; a[6] += s[6] * w2;
        a[7] += s[7] * w2; a[8] += s[8] * w2;
    }
#pragma unroll
    for (int off = 32; off > 0; off >>= 1)
#pragma unroll
        for (int j = 0; j < 9; j++) a[j] += __shfl_down(a[j], off, 64);
    if (lane == 0) {
        float cinv = 1.0f / fmaxf((float)(s1 - s0), 1.0f);
#pragma unroll
        for (int j = 0; j < 9; j++) sh_mean[(size_t)n * 9 + j] = a[j] * cinv;
    }
}

__global__ void k_sh_finish(const float* __restrict__ sh_mean,
                            const float* __restrict__ pos, const float* __restrict__ com,
                            const int* __restrict__ bid, const float* __restrict__ msgC,
                            float* __restrict__ sh) {
    int n = blockIdx.x * blockDim.x + threadIdx.x;
    if (n >= NA) return;
    int b = bid[n];
    float dx = pos[n * 3 + 0] - com[b * 3 + 0];
    float dy = pos[n * 3 + 1] - com[b * 3 + 1];
    float dz = pos[n * 3 + 2] - com[b * 3 + 2];
    float s[9];
    sph9(dx, dy, dz, s);
    float w2 = msgC[n * 3 + 2];
    sh[n * 9 + 0] = 0.0f;
    sh[n * 9 + 1] = 0.0f;
    sh[n * 9 + 2] = 0.0f;
    sh[n * 9 + 3] = 0.0f;
#pragma unroll
    for (int j = 4; j < 9; j++)
        sh[n * 9 + j] = sh_mean[(size_t)n * 9 + j] + s[j] * w2;
}

// fused per-node gather: Xn build (all 128 threads) + p/s aggregation + update
__global__ __launch_bounds__(128) void k_gather_nx(
    const int* __restrict__ ptr, const int* __restrict__ col_s,
    const unsigned short* __restrict__ bufMb, const unsigned short* __restrict__ featb,
    const float* __restrict__ pos, const float* __restrict__ sh,
    const float* __restrict__ psc, const float* __restrict__ ssc,
    unsigned short* __restrict__ Xnb,
    float* __restrict__ pos_new, float* __restrict__ sh_new)
{
    int n = blockIdx.x;
    int tid = threadIdx.x;
    int s0 = ptr[n], s1 = ptr[n + 1];
    float cinv = 1.0f / fmaxf((float)(s1 - s0), 1.0f);

    float sum = 0.0f;
    for (int e = s0; e < s1; e++) sum += bf2f(bufMb[(size_t)e * 128 + tid]);
    Xnb[(size_t)n * 256 + tid] = featb[(size_t)n * 128 + tid];
    Xnb[(size_t)n * 256 + 128 + tid] = f2bf(sum * cinv);

    if (tid < 64) {
        int lane = tid;
        float px = pos[n * 3 + 0], py = pos[n * 3 + 1], pz = pos[n * 3 + 2];
        float shn[9];
#pragma unroll
        for (int j = 0; j < 9; j++) shn[j] = sh[(size_t)n * 9 + j];
        float a[12];
#pragma unroll
        for (int j = 0; j < 12; j++) a[j] = 0.0f;
        for (int e = s0 + lane; e < s1; e += 64) {
            int c = col_s[e];
            float p = psc[e];
            a[0] += (px - pos[c * 3 + 0]) * p;
            a[1] += (py - pos[c * 3 + 1]) * p;
            a[2] += (pz - pos[c * 3 + 2]) * p;
            float w0 = ssc[e * 3 + 0], w1 = ssc[e * 3 + 1], w2 = ssc[e * 3 + 2];
            const float* sc = sh + (size_t)c * 9;
            a[3]  += (shn[0] - sc[0]) * w0;
            a[4]  += (shn[1] - sc[1]) * w1;
            a[5]  += (shn[2] - sc[2]) * w1;
            a[6]  += (shn[3] - sc[3]) * w1;
            a[7]  += (shn[4] - sc[4]) * w2;
            a[8]  += (shn[5] - sc[5]) * w2;
            a[9]  += (shn[6] - sc[6]) * w2;
            a[10] += (shn[7] - sc[7]) * w2;
            a[11] += (shn[8] - sc[8]) * w2;
        }
#pragma unroll
        for (int off = 32; off > 0; off >>= 1)
#pragma unroll
            for (int j = 0; j < 12; j++) a[j] += __shfl_down(a[j], off, 64);
        if (lane == 0) {
            pos_new[n * 3 + 0] = px + a[0] * cinv;
            pos_new[n * 3 + 1] = py + a[1] * cinv;
            pos_new[n * 3 + 2] = pz + a[2] * cinv;
#pragma unroll
            for (int j = 0; j < 9; j++) sh_new[(size_t)n * 9 + j] = shn[j] + a[3 + j] * cinv;
        }
    }
}

__global__ __launch_bounds__(192) void k_pool_pred(
    const int* __restrict__ gptr, const float* __restrict__ feat,
    const float* __restrict__ pos, const float* __restrict__ sh,
    const float* __restrict__ Wp, const float* __restrict__ bp,
    float* __restrict__ out) {
    __shared__ float pl[140];
    int g = blockIdx.x;
    int c = threadIdx.x;
    int s0 = gptr[g], s1 = gptr[g + 1];
    if (c < 140) {
        float sum = 0.0f;
        for (int n = s0; n < s1; n++) {
            float v;
            if (c < 128)      v = feat[(size_t)n * 128 + c];
            else if (c < 131) v = pos[n * 3 + (c - 128)];
            else              v = sh[(size_t)n * 9 + (c - 131)];
            sum += v;
        }
        pl[c] = sum;
    }
    __syncthreads();
    if (c < 64) {
        float s = 0.0f;
        for (int k = c; k < 140; k += 64) s += pl[k] * Wp[k];
#pragma unroll
        for (int off = 32; off > 0; off >>= 1) s += __shfl_down(s, off, 64);
        if (c == 0) out[g] = s + bp[0];
    }
}

// ---------------------------------------------------------------------------
extern "C" void kernel_launch(void* const* d_in, const int* in_sizes, int n_in,
                              void* d_out, int out_size, void* d_ws, size_t ws_size,
                              hipStream_t stream) {
    const int*   atoms  = (const int*)d_in[0];
    const int*   eidx   = (const int*)d_in[1];
    const int*   row    = eidx;
    const int*   col    = eidx + NE;
    const int*   bid    = (const int*)d_in[2];
    const float* pos_in = (const float*)d_in[3];
    const float* emb    = (const float*)d_in[4];
    const float* Wsi1   = (const float*)d_in[5];
    const float* bsi1   = (const float*)d_in[6];
    const float* Wsi2   = (const float*)d_in[7];
    const float* bsi2   = (const float*)d_in[8];
    const float* WsiC1  = (const float*)d_in[9];
    const float* bsiC1  = (const float*)d_in[10];
    const float* WsiC2  = (const float*)d_in[11];
    const float* bsiC2  = (const float*)d_in[12];
    const float* Wm1    = (const float*)d_in[13];
    const float* bm1    = (const float*)d_in[14];
    const float* Wm2    = (const float*)d_in[15];
    const float* bm2    = (const float*)d_in[16];
    const float* Wp1    = (const float*)d_in[17];
    const float* bp1    = (const float*)d_in[18];
    const float* Wp2    = (const float*)d_in[19];
    const float* bp2    = (const float*)d_in[20];
    const float* Wn1    = (const float*)d_in[21];
    const float* bn1    = (const float*)d_in[22];
    const float* Wn2    = (const float*)d_in[23];
    const float* bn2    = (const float*)d_in[24];
    const float* Ws1    = (const float*)d_in[25];
    const float* bs1    = (const float*)d_in[26];
    const float* Ws2    = (const float*)d_in[27];
    const float* bs2    = (const float*)d_in[28];
    const float* Wpred  = (const float*)d_in[29];
    const float* bpred  = (const float*)d_in[30];

    float* base = (float*)d_ws;
    size_t off = 0;
    auto alloc = [&](size_t nfl) { float* r = base + off; off += nfl; return r; };
    unsigned short* bufHb = (unsigned short*)alloc((size_t)NE * DF / 2);
    unsigned short* bufMb = (unsigned short*)alloc((size_t)NE * DF / 2);
    unsigned short* featb = (unsigned short*)alloc((size_t)NAP * DF / 2);
    unsigned short* hnb   = (unsigned short*)alloc((size_t)NAP * DF / 2);
    unsigned short* Xnb   = (unsigned short*)alloc((size_t)NAP * 256 / 2);
    unsigned short* F12   = (unsigned short*)alloc((size_t)NAP * 256 / 2);
    unsigned short* WT    = (unsigned short*)alloc(WT_TOTAL / 2);
    float* feat    = alloc((size_t)NAP * DF);
    float* sc3     = alloc((size_t)NE * 3);
    float* psc     = alloc(NE);
    float* pos0    = alloc((size_t)NA * 3 + 4);
    float* pos1    = alloc((size_t)NA * 3 + 4);
    float* sh0     = alloc((size_t)NA * 9 + 4);
    float* sh1     = alloc((size_t)NA * 9 + 4);
    float* sh_mean = alloc((size_t)NA * 9 + 4);
    float* com     = alloc(NG * 3 + 4);
    float* msgC    = alloc((size_t)NA * 3 + 4);
    int* cnt_row   = (int*)alloc(NA);
    int* ptr       = (int*)alloc(NA + 4);
    int* cursor    = (int*)alloc(NA);
    int* gptr      = (int*)alloc(NG + 4);
    int* row_s     = (int*)alloc(NE);
    int* col_s     = (int*)alloc(NE);
    int* btot      = (int*)alloc(64);

    const dim3 B256(256);
    const int gE = NE / 128;                    // 1250
    const int gE8 = NE / 32;                    // 5000 (8 threads/edge)
    const int gN = NAP / 128;                   // 79
    const dim3 gF(gN, 2);

    // ---------- setup: weights, sort, graph ranges ----------
    hipMemsetAsync(cnt_row, 0, NA * sizeof(int), stream);
    k_prep_w<<<(WT_TOTAL + 255) / 256, B256, 0, stream>>>(Wsi1, WsiC1, Wm1, Wm2, Wp1, Ws1, Wn1, Wn2, WT);
    k_init_feat<<<(NA * DF + 255) / 256, B256, 0, stream>>>(atoms, emb, feat, featb);
    k_copy_pos<<<(NA * 3 + 255) / 256, B256, 0, stream>>>(pos_in, pos0);
    k_count_edges<<<(NE + 255) / 256, B256, 0, stream>>>(row, cnt_row);
    k_scan_block<<<NSB, B256, 0, stream>>>(cnt_row, ptr, btot);
    k_scan_tot<<<1, 64, 0, stream>>>(btot);
    k_scan_add<<<NSB, B256, 0, stream>>>(ptr, btot);
    k_copy_cursor<<<NSB, B256, 0, stream>>>(ptr, cursor);
    k_sort<<<(NE + 255) / 256, B256, 0, stream>>>(row, col, cursor, row_s, col_s);
    k_gptr<<<(NA + 255) / 256, B256, 0, stream>>>(bid, gptr);
    k_com_g<<<NG, 64, 0, stream>>>(pos_in, gptr, com);

    // ---------- initial sh ----------
    k_fgemm<<<gF, B256, 0, stream>>>(featb, WT + OFF_SIRC, F12);
    k_edge_si<<<gE, B256, 0, stream>>>(row_s, col_s, F12, pos0, Wsi1, bsi1, Wsi2, bsi2, sc3);
    k_gather_sph<<<NA, 64, 0, stream>>>(ptr, col_s, pos0, sc3, sh_mean);
    gemm_mfma<128, true, 3, false><<<gN, B256, 0, stream>>>(
        featb, WT + OFF_SICTR, bsiC1, NA, nullptr, nullptr, WsiC2, bsiC2, msgC);
    k_sh_finish<<<(NA + 255) / 256, B256, 0, stream>>>(sh_mean, pos0, com, bid, msgC, sh0);

    float* posA = pos0; float* posB = pos1;
    float* shA = sh0;   float* shB = sh1;

    // ---------- layers ----------
    for (int l = 0; l < NL; l++) {
        const unsigned short* wtL = WT + LBASE + (size_t)l * LSIZE;
        const float* cm1 = bm1 + l * 128;
        const float* wtail = Wm1 + (size_t)l * 33280 + 256 * 128;  // rows 256..259
        const float* cm2 = bm2 + l * 128;
        const float* cp1 = bp1 + l * 128;
        const float* wp2 = Wp2 + (size_t)l * 128;
        const float* cp2 = bp2 + l;
        const float* cn1 = bn1 + l * 128;
        const float* cn2 = bn2 + l * 128;
        const float* cs1 = bs1 + l * 128;
        const float* ws2 = Ws2 + (size_t)l * 128 * 3;
        const float* cs2 = bs2 + l * 3;

        k_fgemm<<<gF, B256, 0, stream>>>(featb, wtL + LOFF_MRC, F12);
        k_edge_h<<<gE8, B256, 0, stream>>>(row_s, col_s, F12, posA, shA, wtail, cm1, bufHb);
        gemm_mfma<128, true, 0, false><<<gE, B256, 0, stream>>>(
            bufHb, wtL + LOFF_M2, cm2, NE, bufMb, nullptr, nullptr, nullptr, nullptr);
        gemm_mfma<128, true, 1, false><<<gE, B256, 0, stream>>>(
            bufMb, wtL + LOFF_P1, cp1, NE, nullptr, nullptr, wp2, cp2, psc);
        gemm_mfma<128, true, 3, false><<<gE, B256, 0, stream>>>(
            bufMb, wtL + LOFF_S1, cs1, NE, nullptr, nullptr, ws2, cs2, sc3);
        k_gather_nx<<<NA, 128, 0, stream>>>(ptr, col_s, bufMb, featb, posA, shA, psc, sc3,
                                            Xnb, posB, shB);
        gemm_mfma<256, true, 0, false><<<gN, B256, 0, stream>>>(
            Xnb, wtL + LOFF_N1, cn1, NA, hnb, nullptr, nullptr, nullptr, nullptr);
        gemm_mfma<128, false, 0, true><<<gN, B256, 0, stream>>>(
            hnb, wtL + LOFF_N2, cn2, NA, featb, feat, nullptr, nullptr, nullptr);

        float* tp = posA; posA = posB; posB = tp;
        float* ts = shA;  shA = shB;  shB = ts;
    }

    // ---------- pooling + prediction ----------
    k_pool_pred<<<NG, 192, 0, stream>>>(gptr, feat, posA, shA, Wpred, bpred, (float*)d_out);
}